// Round 1
// baseline (55581.812 us; speedup 1.0000x reference)
//
#include <hip/hip_runtime.h>

#define T_LEN 16384
#define NT 1024
#define NBLK 32
#define COLS_PER_BLK 32
#define NTHREADS 1024

// ws layout (float index):
//   [0,1024)     alphaA
//   [1024,2048)  alphaB
//   [2048,2112)  maxbuf[2][32]
//   [2112]       gold score
//   [2116]       step counter (unsigned)

__global__ __launch_bounds__(1024) void crf_init(const float* __restrict__ emit,
                                                 const float* __restrict__ strans,
                                                 float* __restrict__ ws) {
  int tid = threadIdx.x;
  float a0 = strans[tid] + emit[tid];   // alpha_0 = strans + emit[0]
  ws[tid] = a0;
  // block max of alpha_0 -> maxbuf[0][0..31]
  float m = a0;
#pragma unroll
  for (int o = 32; o; o >>= 1) m = fmaxf(m, __shfl_xor(m, o));
  __shared__ float sm[16];
  if ((tid & 63) == 0) sm[tid >> 6] = m;
  __syncthreads();
  if (tid < 32) {
    float mm = sm[tid & 15];
#pragma unroll
    for (int o = 8; o; o >>= 1) mm = fmaxf(mm, __shfl_xor(mm, o));
    ws[2048 + tid] = mm;
  }
  if (tid == 0) {
    *((unsigned*)(ws + 2116)) = 0u;
  }
}

__global__ __launch_bounds__(1024) void crf_score(const float* __restrict__ emit,
                                                  const int* __restrict__ y,
                                                  const float* __restrict__ trans,
                                                  const float* __restrict__ strans,
                                                  const float* __restrict__ etrans,
                                                  float* __restrict__ ws) {
  int tid = threadIdx.x;
  float local = 0.f;
  for (int t = tid; t < T_LEN; t += NTHREADS) {
    int yt = y[t];
    local += emit[t * NT + yt];
    if (t > 0) local += trans[y[t - 1] * NT + yt];
  }
  if (tid == 0) local += strans[y[0]];
  if (tid == NTHREADS - 1) local += etrans[y[T_LEN - 1]];
#pragma unroll
  for (int o = 32; o; o >>= 1) local += __shfl_xor(local, o);
  __shared__ float sm[16];
  if ((tid & 63) == 0) sm[tid >> 6] = local;
  __syncthreads();
  if (tid == 0) {
    float s = 0.f;
    for (int i = 0; i < 16; ++i) s += sm[i];
    ws[2112] = s;
  }
}

__global__ __launch_bounds__(1024) void crf_scan(const float* __restrict__ emit,
                                                 const float* __restrict__ trans,
                                                 float* ws) {
  const int tid = threadIdx.x;
  const int blk = blockIdx.x;
  const int l = tid & 63;
  const int w = tid >> 6;
  const int sub = l & 31;
  const int colLocal = 2 * w + (l >> 5);
  const int col = blk * COLS_PER_BLK + colLocal;

  float* alphaA = ws;
  float* alphaB = ws + 1024;
  float* maxbuf = ws + 2048;                 // [2][32]
  unsigned* counter = (unsigned*)(ws + 2116);

  // P fragment in registers: p[4r+i] = exp(trans[j, col]), j = 4*sub + 128*r + i
  float p[32];
#pragma unroll
  for (int r = 0; r < 8; ++r) {
#pragma unroll
    for (int i = 0; i < 4; ++i) {
      int j = 4 * sub + 128 * r + i;
      p[4 * r + i] = __expf(trans[j * NT + col]);
    }
  }

  __shared__ __align__(16) float aS[1024];
  __shared__ float wS[32];

  for (int t = 1; t < T_LEN; ++t) {
    const float* aIn = (t & 1) ? alphaA : alphaB;
    float* aOut      = (t & 1) ? alphaB : alphaA;
    const float* mIn = maxbuf + (((t - 1) & 1) << 5);
    float* mOut      = maxbuf + ((t & 1) << 5);

    // prefetch emit for this step before waiting
    float e = emit[t * NT + col];

    if (w == 0) {
      unsigned tgt = (unsigned)(NBLK * (t - 1));
      while (__hip_atomic_load(counter, __ATOMIC_ACQUIRE, __HIP_MEMORY_SCOPE_AGENT) < tgt)
        __builtin_amdgcn_s_sleep(1);
    }
    __syncthreads();  // release whole block once all producers for step t-1 done

    float av = __hip_atomic_load(aIn + tid, __ATOMIC_RELAXED, __HIP_MEMORY_SCOPE_AGENT);
    float mv = __hip_atomic_load(mIn + sub, __ATOMIC_RELAXED, __HIP_MEMORY_SCOPE_AGENT);
#pragma unroll
    for (int o = 16; o; o >>= 1) mv = fmaxf(mv, __shfl_xor(mv, o));  // exact global max of alpha

    aS[tid] = __expf(av - mv);
    __syncthreads();

    float s = 0.f;
#pragma unroll
    for (int r = 0; r < 8; ++r) {
      float4 a4 = *reinterpret_cast<const float4*>(&aS[4 * sub + 128 * r]);
      s = fmaf(a4.x, p[4 * r + 0], s);
      s = fmaf(a4.y, p[4 * r + 1], s);
      s = fmaf(a4.z, p[4 * r + 2], s);
      s = fmaf(a4.w, p[4 * r + 3], s);
    }
#pragma unroll
    for (int o = 16; o; o >>= 1) s += __shfl_xor(s, o);  // reduce over the column's 32 lanes

    float anew = e + mv + __logf(s);
    if (sub == 0) {
      __hip_atomic_store(aOut + col, anew, __ATOMIC_RELAXED, __HIP_MEMORY_SCOPE_AGENT);
      wS[colLocal] = anew;
    }
    __syncthreads();
    if (w == 0) {
      float m2 = wS[sub];
#pragma unroll
      for (int o = 16; o; o >>= 1) m2 = fmaxf(m2, __shfl_xor(m2, o));
      if (tid == 0) {
        __hip_atomic_store(mOut + blk, m2, __ATOMIC_RELAXED, __HIP_MEMORY_SCOPE_AGENT);
        __hip_atomic_fetch_add(counter, 1u, __ATOMIC_RELEASE, __HIP_MEMORY_SCOPE_AGENT);
      }
    }
  }
}

__global__ __launch_bounds__(1024) void crf_final(const float* __restrict__ etrans,
                                                  const float* __restrict__ ws,
                                                  float* __restrict__ out) {
  int tid = threadIdx.x;
  // final alpha is in alphaB (last step t=16383 is odd)
  float v = ws[1024 + tid] + etrans[tid];
  float m = v;
#pragma unroll
  for (int o = 32; o; o >>= 1) m = fmaxf(m, __shfl_xor(m, o));
  __shared__ float sm[16];
  __shared__ float sM;
  if ((tid & 63) == 0) sm[tid >> 6] = m;
  __syncthreads();
  if (tid == 0) {
    float mm = sm[0];
    for (int i = 1; i < 16; ++i) mm = fmaxf(mm, sm[i]);
    sM = mm;
  }
  __syncthreads();
  float M = sM;
  float s = __expf(v - M);
#pragma unroll
  for (int o = 32; o; o >>= 1) s += __shfl_xor(s, o);
  __shared__ float ss[16];
  if ((tid & 63) == 0) ss[tid >> 6] = s;
  __syncthreads();
  if (tid == 0) {
    float tot = 0.f;
    for (int i = 0; i < 16; ++i) tot += ss[i];
    float logZ = M + __logf(tot);
    out[0] = logZ - ws[2112];
  }
}

extern "C" void kernel_launch(void* const* d_in, const int* in_sizes, int n_in,
                              void* d_out, int out_size, void* d_ws, size_t ws_size,
                              hipStream_t stream) {
  const float* emit = (const float*)d_in[0];
  const int* y = (const int*)d_in[1];
  const float* trans = (const float*)d_in[2];
  const float* strans = (const float*)d_in[3];
  const float* etrans = (const float*)d_in[4];
  float* ws = (float*)d_ws;
  float* out = (float*)d_out;

  crf_init<<<1, NTHREADS, 0, stream>>>(emit, strans, ws);
  crf_score<<<1, NTHREADS, 0, stream>>>(emit, y, trans, strans, etrans, ws);
  crf_scan<<<NBLK, NTHREADS, 0, stream>>>(emit, trans, ws);
  crf_final<<<1, NTHREADS, 0, stream>>>(etrans, ws, out);
}

// Round 2
// 27265.543 us; speedup vs baseline: 2.0385x; 2.0385x over previous
//
#include <hip/hip_runtime.h>

#define T_LEN 16384
#define NT 1024
#define NBLK 32
#define NTHREADS 1024

typedef unsigned long long u64;
typedef unsigned int u32;

// ws layout:
//   u64 buf0[1024]   @ bytes [0, 8192)        tagged alpha, even parity
//   u64 buf1[1024]   @ bytes [8192, 16384)    tagged alpha, odd parity
//   float gold       @ float index 4096 (byte 16384)
// tagged word = (step_tag << 32) | float_bits

__device__ __forceinline__ u64 pack_tag(u32 tag, float v) {
  return ((u64)tag << 32) | (u64)__float_as_uint(v);
}

__global__ __launch_bounds__(1024) void crf_init(const float* __restrict__ emit,
                                                 const float* __restrict__ strans,
                                                 u64* __restrict__ buf) {
  int tid = threadIdx.x;
  float a0 = strans[tid] + emit[tid];  // alpha_0 = strans + emit[0]
  buf[tid] = pack_tag(0u, a0);         // plain store; kernel-end flush publishes it
}

__global__ __launch_bounds__(1024) void crf_score(const float* __restrict__ emit,
                                                  const int* __restrict__ y,
                                                  const float* __restrict__ trans,
                                                  const float* __restrict__ strans,
                                                  const float* __restrict__ etrans,
                                                  float* __restrict__ ws) {
  int tid = threadIdx.x;
  float local = 0.f;
  for (int t = tid; t < T_LEN; t += NTHREADS) {
    int yt = y[t];
    local += emit[t * NT + yt];
    if (t > 0) local += trans[y[t - 1] * NT + yt];
  }
  if (tid == 0) local += strans[y[0]];
  if (tid == NTHREADS - 1) local += etrans[y[T_LEN - 1]];
#pragma unroll
  for (int o = 32; o; o >>= 1) local += __shfl_xor(local, o);
  __shared__ float sm[16];
  if ((tid & 63) == 0) sm[tid >> 6] = local;
  __syncthreads();
  if (tid == 0) {
    float s = 0.f;
    for (int i = 0; i < 16; ++i) s += sm[i];
    ws[4096] = s;
  }
}

__global__ __launch_bounds__(1024) void crf_scan(const float* __restrict__ emit,
                                                 const float* __restrict__ trans,
                                                 u64* buf) {
  const int tid = threadIdx.x;
  const int blk = blockIdx.x;
  const int l = tid & 63;
  const int w = tid >> 6;
  const int sub = l & 31;              // lane within the 32-lane column group
  const int colLocal = 2 * w + (l >> 5);
  const int col = blk * 32 + colLocal;

  u64* buf0 = buf;
  u64* buf1 = buf + NT;

  // P fragment in registers: p[4r+i] = exp(trans[j, col]), j = 4*sub + 128*r + i
  float p[32];
#pragma unroll
  for (int r = 0; r < 8; ++r) {
#pragma unroll
    for (int i = 0; i < 4; ++i) {
      int j = 4 * sub + 128 * r + i;
      p[4 * r + i] = __expf(trans[j * NT + col]);
    }
  }

  __shared__ __align__(16) float aS[1024];
  __shared__ float wS[32];

  // Initial block-local scale M = max over this block's 32 columns of alpha_0.
  // (Exact global max not needed: scale only keeps exp() in range.)
  float M;
  {
    u64 wd = __hip_atomic_load(buf0 + (blk * 32 + sub), __ATOMIC_RELAXED,
                               __HIP_MEMORY_SCOPE_AGENT);
    float v = __uint_as_float((u32)wd);
#pragma unroll
    for (int o = 16; o; o >>= 1) v = fmaxf(v, __shfl_xor(v, o));
    M = v;
  }

  for (int t = 1; t < T_LEN; ++t) {
    u64* bIn  = (t & 1) ? buf0 : buf1;   // holds tag t-1
    u64* bOut = (t & 1) ? buf1 : buf0;   // receives tag t

    float e = emit[t * NT + col];        // prefetch; consumed after poll

    // Poll own tagged word — the data IS the flag. Relaxed agent atomics
    // bypass L1/L2 per-access: no fences, no RMW, no L2 writeback/invalidate.
    const u32 want = (u32)(t - 1);
    u64 wd = __hip_atomic_load(bIn + tid, __ATOMIC_RELAXED, __HIP_MEMORY_SCOPE_AGENT);
    while ((u32)(wd >> 32) != want)
      wd = __hip_atomic_load(bIn + tid, __ATOMIC_RELAXED, __HIP_MEMORY_SCOPE_AGENT);
    float av = __uint_as_float((u32)wd);

    aS[tid] = __expf(av - M);
    __syncthreads();

    float s = 0.f;
#pragma unroll
    for (int r = 0; r < 8; ++r) {
      float4 a4 = *reinterpret_cast<const float4*>(&aS[4 * sub + 128 * r]);
      s = fmaf(a4.x, p[4 * r + 0], s);
      s = fmaf(a4.y, p[4 * r + 1], s);
      s = fmaf(a4.z, p[4 * r + 2], s);
      s = fmaf(a4.w, p[4 * r + 3], s);
    }
#pragma unroll
    for (int o = 16; o; o >>= 1) s += __shfl_xor(s, o);

    float anew = e + M + __logf(s);
    if (sub == 0) {
      wS[colLocal] = anew;
      __hip_atomic_store(bOut + col, pack_tag((u32)t, anew), __ATOMIC_RELAXED,
                         __HIP_MEMORY_SCOPE_AGENT);
    }
    __syncthreads();

    // Next step's block-local scale: max over this block's 32 fresh columns.
    // Every wave computes it redundantly from LDS — no extra barrier needed
    // (wS is next written only after all threads pass the next __syncthreads).
    float mv = wS[sub];
#pragma unroll
    for (int o = 16; o; o >>= 1) mv = fmaxf(mv, __shfl_xor(mv, o));
    M = mv;
  }
}

__global__ __launch_bounds__(1024) void crf_final(const float* __restrict__ etrans,
                                                  const u64* __restrict__ buf,
                                                  const float* __restrict__ ws,
                                                  float* __restrict__ out) {
  int tid = threadIdx.x;
  // final alpha (t = 16383, odd) lives in buf1, tag 16383
  float v = __uint_as_float((u32)buf[NT + tid]) + etrans[tid];
  float m = v;
#pragma unroll
  for (int o = 32; o; o >>= 1) m = fmaxf(m, __shfl_xor(m, o));
  __shared__ float sm[16];
  __shared__ float sM;
  if ((tid & 63) == 0) sm[tid >> 6] = m;
  __syncthreads();
  if (tid == 0) {
    float mm = sm[0];
    for (int i = 1; i < 16; ++i) mm = fmaxf(mm, sm[i]);
    sM = mm;
  }
  __syncthreads();
  float Mv = sM;
  float s = __expf(v - Mv);
#pragma unroll
  for (int o = 32; o; o >>= 1) s += __shfl_xor(s, o);
  __shared__ float ss[16];
  if ((tid & 63) == 0) ss[tid >> 6] = s;
  __syncthreads();
  if (tid == 0) {
    float tot = 0.f;
    for (int i = 0; i < 16; ++i) tot += ss[i];
    float logZ = Mv + __logf(tot);
    out[0] = logZ - ws[4096];
  }
}

extern "C" void kernel_launch(void* const* d_in, const int* in_sizes, int n_in,
                              void* d_out, int out_size, void* d_ws, size_t ws_size,
                              hipStream_t stream) {
  const float* emit = (const float*)d_in[0];
  const int* y = (const int*)d_in[1];
  const float* trans = (const float*)d_in[2];
  const float* strans = (const float*)d_in[3];
  const float* etrans = (const float*)d_in[4];
  u64* buf = (u64*)d_ws;
  float* ws = (float*)d_ws;
  float* out = (float*)d_out;

  crf_init<<<1, NTHREADS, 0, stream>>>(emit, strans, buf);
  crf_score<<<1, NTHREADS, 0, stream>>>(emit, y, trans, strans, etrans, ws);
  crf_scan<<<NBLK, NTHREADS, 0, stream>>>(emit, trans, buf);
  crf_final<<<1, NTHREADS, 0, stream>>>(etrans, buf, ws, out);
}

// Round 3
// 24836.354 us; speedup vs baseline: 2.2379x; 1.0978x over previous
//
#include <hip/hip_runtime.h>

#define T_LEN 16384
#define NT 1024
#define NBLK 64
#define CPB 16      // columns per block
#define NTHR 256    // 4 waves

typedef unsigned long long u64;
typedef unsigned int u32;

// ws layout:
//   u64 buf0[1024] @ bytes [0,8192)      tagged alpha, even parity
//   u64 buf1[1024] @ bytes [8192,16384)  tagged alpha, odd parity
//   float gold     @ float index 4096
// tagged word = (step_tag << 32) | float_bits

__device__ __forceinline__ u64 pack_tag(u32 tag, float v) {
  return ((u64)tag << 32) | (u64)__float_as_uint(v);
}
__device__ __forceinline__ u64 ld_tag(const u64* p) {
  return __hip_atomic_load(p, __ATOMIC_RELAXED, __HIP_MEMORY_SCOPE_AGENT);
}
__device__ __forceinline__ void st_tag(u64* p, u64 v) {
  __hip_atomic_store(p, v, __ATOMIC_RELAXED, __HIP_MEMORY_SCOPE_AGENT);
}

__global__ __launch_bounds__(1024) void crf_init(const float* __restrict__ emit,
                                                 const float* __restrict__ strans,
                                                 u64* __restrict__ buf) {
  int tid = threadIdx.x;
  float a0 = strans[tid] + emit[tid];
  buf[tid] = pack_tag(0u, a0);
}

__global__ __launch_bounds__(1024) void crf_score(const float* __restrict__ emit,
                                                  const int* __restrict__ y,
                                                  const float* __restrict__ trans,
                                                  const float* __restrict__ strans,
                                                  const float* __restrict__ etrans,
                                                  float* __restrict__ ws) {
  int tid = threadIdx.x;
  float local = 0.f;
  for (int t = tid; t < T_LEN; t += 1024) {
    int yt = y[t];
    local += emit[t * NT + yt];
    if (t > 0) local += trans[y[t - 1] * NT + yt];
  }
  if (tid == 0) local += strans[y[0]];
  if (tid == 1023) local += etrans[y[T_LEN - 1]];
#pragma unroll
  for (int o = 32; o; o >>= 1) local += __shfl_xor(local, o);
  __shared__ float sm[16];
  if ((tid & 63) == 0) sm[tid >> 6] = local;
  __syncthreads();
  if (tid == 0) {
    float s = 0.f;
    for (int i = 0; i < 16; ++i) s += sm[i];
    ws[4096] = s;
  }
}

__global__ __launch_bounds__(NTHR, 1) void crf_scan(const float* __restrict__ emit,
                                                    const float* __restrict__ trans,
                                                    u64* buf) {
  const int tid = threadIdx.x;
  const int blk = blockIdx.x;
  const int c = tid & 15;        // local column
  const int chunk = tid >> 4;    // j-chunk 0..15 (64 j's each)
  const int col = blk * CPB + c;
  const int wv = tid >> 6;       // wave 0..3

  u64* buf0 = buf;
  u64* buf1 = buf + NT;

  // P fragment: p[4i+x] = exp(trans[j, col]), j = 64*chunk + ((4i + 8*chunk)&63) + x
  // (the 8*chunk stagger makes the 4 distinct LDS lines per wave-read hit
  //  disjoint bank quads -> conflict-free broadcast reads)
  float p[64];
  const int jbase = chunk * 64;
#pragma unroll
  for (int i = 0; i < 16; ++i) {
    int off = (4 * i + 8 * chunk) & 63;
#pragma unroll
    for (int x = 0; x < 4; ++x)
      p[4 * i + x] = __expf(trans[(jbase + off + x) * NT + col]);
  }

  __shared__ __align__(16) float aS[NT];
  __shared__ float partS[64];    // [wave][16 cols]

  // initial block-local scale M = max over this block's 16 columns of alpha_0
  float M;
  {
    u64 wd = ld_tag(buf0 + col);
    float v = __uint_as_float((u32)wd);
#pragma unroll
    for (int o = 8; o; o >>= 1) v = fmaxf(v, __shfl_xor(v, o));
    M = v;
  }

  const int i0 = tid, i1 = tid + 256, i2 = tid + 512, i3 = tid + 768;

  for (int t = 1; t < T_LEN; ++t) {
    u64* bIn  = (t & 1) ? buf0 : buf1;   // holds tag t-1
    u64* bOut = (t & 1) ? buf1 : buf0;   // receives tag t

    float e = emit[t * NT + col];        // in flight during the poll below

    // poll 4 tagged words per thread, kept independently in flight
    const u32 want = (u32)(t - 1);
    u64 w0 = ld_tag(bIn + i0), w1 = ld_tag(bIn + i1);
    u64 w2 = ld_tag(bIn + i2), w3 = ld_tag(bIn + i3);
    for (;;) {
      bool s0 = (u32)(w0 >> 32) != want;
      bool s1 = (u32)(w1 >> 32) != want;
      bool s2 = (u32)(w2 >> 32) != want;
      bool s3 = (u32)(w3 >> 32) != want;
      if (!(s0 | s1 | s2 | s3)) break;
      if (s0) w0 = ld_tag(bIn + i0);
      if (s1) w1 = ld_tag(bIn + i1);
      if (s2) w2 = ld_tag(bIn + i2);
      if (s3) w3 = ld_tag(bIn + i3);
    }
    aS[i0] = __expf(__uint_as_float((u32)w0) - M);
    aS[i1] = __expf(__uint_as_float((u32)w1) - M);
    aS[i2] = __expf(__uint_as_float((u32)w2) - M);
    aS[i3] = __expf(__uint_as_float((u32)w3) - M);
    __syncthreads();

    // GEMV: thread owns (col c, j-chunk): 16 broadcast float4 reads + 64 FMA
    float s = 0.f;
    const float4* aV = (const float4*)aS;
#pragma unroll
    for (int i = 0; i < 16; ++i) {
      int off = (4 * i + 8 * chunk) & 63;
      float4 a4 = aV[(jbase + off) >> 2];
      s = fmaf(a4.x, p[4 * i + 0], s);
      s = fmaf(a4.y, p[4 * i + 1], s);
      s = fmaf(a4.z, p[4 * i + 2], s);
      s = fmaf(a4.w, p[4 * i + 3], s);
    }
    // reduce over the wave's 4 chunks (tid bits 4,5)
    s += __shfl_xor(s, 16);
    s += __shfl_xor(s, 32);
    if ((tid & 63) < 16) partS[wv * 16 + c] = s;
    __syncthreads();

    // final cross-wave combine, done redundantly by every thread (4 LDS reads)
    float tot = partS[c] + partS[16 + c] + partS[32 + c] + partS[48 + c];
    float anew = e + M + __logf(tot);
    if (tid < 16) st_tag(bOut + col, pack_tag((u32)t, anew));

    // block-local M for next step: max over this block's 16 fresh columns
    float m2 = anew;
#pragma unroll
    for (int o = 8; o; o >>= 1) m2 = fmaxf(m2, __shfl_xor(m2, o));
    M = m2;
  }
}

__global__ __launch_bounds__(1024) void crf_final(const float* __restrict__ etrans,
                                                  const u64* __restrict__ buf,
                                                  const float* __restrict__ ws,
                                                  float* __restrict__ out) {
  int tid = threadIdx.x;
  // final alpha (t = 16383, odd) lives in buf1
  float v = __uint_as_float((u32)buf[NT + tid]) + etrans[tid];
  float m = v;
#pragma unroll
  for (int o = 32; o; o >>= 1) m = fmaxf(m, __shfl_xor(m, o));
  __shared__ float sm[16];
  __shared__ float sM;
  if ((tid & 63) == 0) sm[tid >> 6] = m;
  __syncthreads();
  if (tid == 0) {
    float mm = sm[0];
    for (int i = 1; i < 16; ++i) mm = fmaxf(mm, sm[i]);
    sM = mm;
  }
  __syncthreads();
  float Mv = sM;
  float s = __expf(v - Mv);
#pragma unroll
  for (int o = 32; o; o >>= 1) s += __shfl_xor(s, o);
  __shared__ float ss[16];
  if ((tid & 63) == 0) ss[tid >> 6] = s;
  __syncthreads();
  if (tid == 0) {
    float tot = 0.f;
    for (int i = 0; i < 16; ++i) tot += ss[i];
    float logZ = Mv + __logf(tot);
    out[0] = logZ - ws[4096];
  }
}

extern "C" void kernel_launch(void* const* d_in, const int* in_sizes, int n_in,
                              void* d_out, int out_size, void* d_ws, size_t ws_size,
                              hipStream_t stream) {
  const float* emit = (const float*)d_in[0];
  const int* y = (const int*)d_in[1];
  const float* trans = (const float*)d_in[2];
  const float* strans = (const float*)d_in[3];
  const float* etrans = (const float*)d_in[4];
  u64* buf = (u64*)d_ws;
  float* ws = (float*)d_ws;
  float* out = (float*)d_out;

  crf_init<<<1, 1024, 0, stream>>>(emit, strans, buf);
  crf_score<<<1, 1024, 0, stream>>>(emit, y, trans, strans, etrans, ws);
  crf_scan<<<NBLK, NTHR, 0, stream>>>(emit, trans, buf);
  crf_final<<<1, 1024, 0, stream>>>(etrans, buf, ws, out);
}